// Round 4
// baseline (51.813 us; speedup 1.0000x reference)
//
#include <hip/hip_runtime.h>
#include <hip/hip_bf16.h>

typedef __attribute__((ext_vector_type(4))) float f32x4;
typedef __attribute__((ext_vector_type(8))) short s16x8;
typedef __attribute__((ext_vector_type(4))) short s16x4;
typedef unsigned int u32;

#define KVBLK 32
#define DHEAD 128
#define VSTR 40    // V^T LDS row stride in bf16 elems (80 B)

__device__ __forceinline__ short f2bf(float x) {
    __hip_bfloat16 h = __float2bfloat16(x);
    return *reinterpret_cast<short*>(&h);
}
__device__ __forceinline__ float bf2f(short s) {
    __hip_bfloat16 h = *reinterpret_cast<__hip_bfloat16*>(&s);
    return __bfloat162float(h);
}

// Pre-convert K,V f32 -> bf16 once (blocks re-used them nq=32 times).
// K is written with 16B-chunk XOR swizzle (chunk ^= row&7) so that a LINEAR
// global_load_lds into LDS yields the bank-conflict-reduced layout (rule #21:
// inverse-swizzled source + swizzled read, linear DMA dest).
__global__ __launch_bounds__(256)
void prep_bf16(const float* __restrict__ K, const float* __restrict__ V,
               short* __restrict__ Kz, short* __restrict__ Vz, int nvec) {
    const int i = blockIdx.x * 256 + threadIdx.x;
    if (i < nvec) {
        const int rk = i >> 4, cc = i & 15;          // row, 16B-chunk
        const float* src = K + ((size_t)rk << 7) + (cc << 3);
        f32x4 a = *reinterpret_cast<const f32x4*>(src);
        f32x4 b = *reinterpret_cast<const f32x4*>(src + 4);
        s16x8 s;
        #pragma unroll
        for (int j = 0; j < 4; ++j) { s[j] = f2bf(a[j]); s[4 + j] = f2bf(b[j]); }
        *reinterpret_cast<s16x8*>(Kz + ((size_t)rk << 7) + ((cc ^ (rk & 7)) << 3)) = s;
    } else {
        const int j = i - nvec;
        if (j < nvec) {
            const float* src = V + ((size_t)j << 3);
            f32x4 a = *reinterpret_cast<const f32x4*>(src);
            f32x4 b = *reinterpret_cast<const f32x4*>(src + 4);
            s16x8 s;
            #pragma unroll
            for (int jj = 0; jj < 4; ++jj) { s[jj] = f2bf(a[jj]); s[4 + jj] = f2bf(b[jj]); }
            *reinterpret_cast<s16x8*>(Vz + ((size_t)j << 3)) = s;
        }
    }
}

// Flash attention, cyclic KV-split S. Block = 2 waves x 16 q-rows, KVBLK=32.
// K tile: global_load_lds DMA (pre-swizzled bf16 source). V tile: bf16 regs
// prefetched one tile ahead (T14), transposed into swizzled LDS.
__global__ __launch_bounds__(128, 4)
void attn_fwd(const float* __restrict__ Q, const short* __restrict__ Kz,
              const short* __restrict__ Vz, const int* __restrict__ VL,
              float* __restrict__ O, short* __restrict__ OPb, float2* __restrict__ ML,
              int B, int n, int m, int S, int rows) {
    __shared__ short Ks[KVBLK * DHEAD];   // 8192 B, swizzled-chunk layout
    __shared__ short Vs[DHEAD * VSTR];    // 10240 B

    const int tid  = threadIdx.x;
    const int lane = tid & 63;
    const int wid  = tid >> 6;     // 0..1
    const int g    = lane >> 4;    // 0..3
    const int qi   = lane & 15;

    const int nq = n >> 5;
    int b, rest;
    if ((B & 7) == 0) {
        const int xcd = blockIdx.x & 7;
        const int sub = blockIdx.x >> 3;
        const int bpx = B >> 3;
        b    = xcd * bpx + (sub % bpx);
        rest = sub / bpx;
    } else {
        const int per = nq * S;
        b    = blockIdx.x / per;
        rest = blockIdx.x % per;
    }
    const int qt = rest / S;
    const int c  = rest - qt * S;

    const int vl = VL[b];
    const int nt = (vl + KVBLK - 1) / KVBLK;
    const int rowbase = b * n + qt * 32 + wid * 16;

    if (c >= nt) {   // empty chunk (cyclic split)
        if (g == 0) ML[(size_t)c * rows + rowbase + qi] = make_float2(-1e30f, 0.f);
        return;
    }

    const float* Qb = Q + (size_t)rowbase * DHEAD;
    const short* Kb = Kz + (size_t)b * m * DHEAD;
    const short* Vb = Vz + (size_t)b * m * DHEAD;

    // ---- Q fragments (f32 source), pre-scaled by 1/sqrt(d)*log2(e) ----
    const float qsc = 0.08838834764831845f * 1.4426950408889634f;
    s16x8 qf[4];
    {
        const float* qp = Qb + qi * DHEAD + g * 8;
        #pragma unroll
        for (int kk = 0; kk < 4; ++kk) {
            f32x4 a  = *reinterpret_cast<const f32x4*>(qp + kk * 32);
            f32x4 cc = *reinterpret_cast<const f32x4*>(qp + kk * 32 + 4);
            s16x8 s;
            #pragma unroll
            for (int j = 0; j < 4; ++j) { s[j] = f2bf(a[j] * qsc); s[4 + j] = f2bf(cc[j] * qsc); }
            qf[kk] = s;
        }
    }

    // K ds_read byte offsets: row=16s+qi (256 B/row), chunk (kk*4+g) ^ (qi&7)
    int kfoff[2][4];
    #pragma unroll
    for (int s = 0; s < 2; ++s)
        #pragma unroll
        for (int kk = 0; kk < 4; ++kk)
            kfoff[s][kk] = (16 * s + qi) * 256 + ((((kk << 2) | g) ^ (qi & 7)) << 4);

    // V^T read byte offsets
    int voff[8];
    #pragma unroll
    for (int dg = 0; dg < 8; ++dg) {
        const int row = qi + (dg << 4);
        voff[dg] = (row * VSTR + ((g << 2) ^ (((row >> 3) & 3) << 2))) * 2;
    }

    // V staging mapping: thread = 4 kv rows x 8 dv cols
    const int kvq  = tid >> 4;          // 0..7
    const int dvo  = tid & 15;          // 0..15
    const int dv0  = dvo << 3;
    const int vswz = (dvo & 3) << 2;    // quad-swizzle for this thread's columns

    f32x4 Oacc[8];
    #pragma unroll
    for (int dg = 0; dg < 8; ++dg) Oacc[dg] = 0.f;
    float mrun = -1e30f, lrun = 0.f;

    // prologue: prefetch V(first tile) into regs
    s16x8 vreg[4];
    {
        const short* vp = Vb + ((size_t)(c * KVBLK) + (kvq << 2)) * DHEAD + dv0;
        #pragma unroll
        for (int r = 0; r < 4; ++r) vreg[r] = *reinterpret_cast<const s16x8*>(vp + r * DHEAD);
    }

    #pragma unroll 1
    for (int t = c; t < nt; t += S) {
        const int base = t * KVBLK;
        __syncthreads();   // A: prev tile's LDS readers done (also drains V prefetch)

        // ---- K tile DMA: each wave copies its 4 KB half, linear dest ----
        {
            const char* gsrc = (const char*)(Kb + (size_t)base * DHEAD);
            #pragma unroll
            for (int j2 = 0; j2 < 4; ++j2) {
                const int off = wid * 4096 + j2 * 1024;
                __builtin_amdgcn_global_load_lds(
                    (const __attribute__((address_space(1))) u32*)(gsrc + off + lane * 16),
                    (__attribute__((address_space(3))) u32*)((char*)Ks + off),
                    16, 0, 0);
            }
        }
        // ---- V(t): transpose vreg -> swizzled V^T LDS ----
        #pragma unroll
        for (int jj = 0; jj < 8; ++jj) {
            s16x4 colv;
            colv[0] = vreg[0][jj]; colv[1] = vreg[1][jj];
            colv[2] = vreg[2][jj]; colv[3] = vreg[3][jj];
            const int dvr = dv0 + jj;
            *reinterpret_cast<s16x4*>((char*)Vs + dvr * (VSTR * 2) + (((kvq << 2) ^ vswz) << 1)) = colv;
        }
        __syncthreads();   // B: K DMA + V writes complete

        // ---- prefetch V(t+S) — flies through QK/softmax/PV ----
        const int tn = t + S;
        if (tn < nt) {
            const short* vp = Vb + ((size_t)(tn * KVBLK) + (kvq << 2)) * DHEAD + dv0;
            #pragma unroll
            for (int r = 0; r < 4; ++r) vreg[r] = *reinterpret_cast<const s16x8*>(vp + r * DHEAD);
        }

        // ---- S^T = K * Q^T ----
        f32x4 Sacc[2];
        #pragma unroll
        for (int s = 0; s < 2; ++s) Sacc[s] = 0.f;
        #pragma unroll
        for (int s = 0; s < 2; ++s)
            #pragma unroll
            for (int kk = 0; kk < 4; ++kk) {
                s16x8 kf = *reinterpret_cast<const s16x8*>((char*)Ks + kfoff[s][kk]);
                Sacc[s] = __builtin_amdgcn_mfma_f32_16x16x32_bf16(kf, qf[kk], Sacc[s], 0, 0, 0);
            }

        // ---- valid_length mask ----
        const int kvrem = vl - base;
        if (kvrem < KVBLK) {
            #pragma unroll
            for (int s = 0; s < 2; ++s)
                #pragma unroll
                for (int r = 0; r < 4; ++r)
                    if (s * 16 + g * 4 + r >= kvrem) Sacc[s][r] = -1e30f;
        }

        // ---- online softmax ----
        float tmax = -1e30f;
        #pragma unroll
        for (int s = 0; s < 2; ++s)
            #pragma unroll
            for (int r = 0; r < 4; ++r) tmax = fmaxf(tmax, Sacc[s][r]);
        tmax = fmaxf(tmax, __shfl_xor(tmax, 16));
        tmax = fmaxf(tmax, __shfl_xor(tmax, 32));
        const float mnew = fmaxf(mrun, tmax);
        const float corr = __builtin_amdgcn_exp2f(mrun - mnew);

        float psum = 0.f;
        #pragma unroll
        for (int s = 0; s < 2; ++s)
            #pragma unroll
            for (int r = 0; r < 4; ++r) {
                const float e = __builtin_amdgcn_exp2f(Sacc[s][r] - mnew);
                Sacc[s][r] = e; psum += e;
            }
        psum += __shfl_xor(psum, 16);
        psum += __shfl_xor(psum, 32);
        lrun = lrun * corr + psum;
        mrun = mnew;

        s16x8 pa;
        #pragma unroll
        for (int r = 0; r < 4; ++r) {
            pa[r]     = f2bf(Sacc[0][r]);
            pa[4 + r] = f2bf(Sacc[1][r]);
        }

        const float rr0 = __shfl(corr, g * 4 + 0);
        const float rr1 = __shfl(corr, g * 4 + 1);
        const float rr2 = __shfl(corr, g * 4 + 2);
        const float rr3 = __shfl(corr, g * 4 + 3);
        #pragma unroll
        for (int dg = 0; dg < 8; ++dg) {
            Oacc[dg][0] *= rr0; Oacc[dg][1] *= rr1;
            Oacc[dg][2] *= rr2; Oacc[dg][3] *= rr3;
        }

        // ---- O += P * V ----
        #pragma unroll
        for (int dg = 0; dg < 8; ++dg) {
            s16x4 v0 = *reinterpret_cast<const s16x4*>((char*)Vs + voff[dg]);
            s16x4 v1 = *reinterpret_cast<const s16x4*>((char*)Vs + voff[dg] + 32);
            s16x8 vf;
            vf[0] = v0[0]; vf[1] = v0[1]; vf[2] = v0[2]; vf[3] = v0[3];
            vf[4] = v1[0]; vf[5] = v1[1]; vf[6] = v1[2]; vf[7] = v1[3];
            Oacc[dg] = __builtin_amdgcn_mfma_f32_16x16x32_bf16(pa, vf, Oacc[dg], 0, 0, 0);
        }
    }

    if (S > 1) {
        if (g == 0) ML[(size_t)c * rows + rowbase + qi] = make_float2(mrun, lrun);
        short* Op = OPb + ((size_t)c * rows + rowbase) * DHEAD;
        #pragma unroll
        for (int dg = 0; dg < 8; ++dg) {
            Op[(g * 4 + 0) * DHEAD + dg * 16 + qi] = f2bf(Oacc[dg][0]);
            Op[(g * 4 + 1) * DHEAD + dg * 16 + qi] = f2bf(Oacc[dg][1]);
            Op[(g * 4 + 2) * DHEAD + dg * 16 + qi] = f2bf(Oacc[dg][2]);
            Op[(g * 4 + 3) * DHEAD + dg * 16 + qi] = f2bf(Oacc[dg][3]);
        }
    } else {
        const float linv = 1.0f / lrun;
        const float l0 = __shfl(linv, g * 4 + 0);
        const float l1 = __shfl(linv, g * 4 + 1);
        const float l2 = __shfl(linv, g * 4 + 2);
        const float l3 = __shfl(linv, g * 4 + 3);
        float* Ob = O + (size_t)rowbase * DHEAD;
        #pragma unroll
        for (int dg = 0; dg < 8; ++dg) {
            Ob[(g * 4 + 0) * DHEAD + dg * 16 + qi] = Oacc[dg][0] * l0;
            Ob[(g * 4 + 1) * DHEAD + dg * 16 + qi] = Oacc[dg][1] * l1;
            Ob[(g * 4 + 2) * DHEAD + dg * 16 + qi] = Oacc[dg][2] * l2;
            Ob[(g * 4 + 3) * DHEAD + dg * 16 + qi] = Oacc[dg][3] * l3;
        }
    }
}

// merge S partials per q-row
__global__ __launch_bounds__(128)
void attn_combine(const short* __restrict__ OPb, const float2* __restrict__ ML,
                  float* __restrict__ O, int S, int rows) {
    const int row = blockIdx.x;
    const int t   = threadIdx.x;
    float M = -1e30f;
    for (int s = 0; s < S; ++s) M = fmaxf(M, ML[(size_t)s * rows + row].x);
    float L = 0.f, acc = 0.f;
    for (int s = 0; s < S; ++s) {
        const float2 ml = ML[(size_t)s * rows + row];
        if (ml.y > 0.f) {
            const float w = exp2f(ml.x - M);
            L += ml.y * w;
            acc += w * bf2f(OPb[((size_t)s * rows + row) * DHEAD + t]);
        }
    }
    O[(size_t)row * DHEAD + t] = acc / L;
}

extern "C" void kernel_launch(void* const* d_in, const int* in_sizes, int n_in,
                              void* d_out, int out_size, void* d_ws, size_t ws_size,
                              hipStream_t stream) {
    const float* Q  = (const float*)d_in[0];
    const float* K  = (const float*)d_in[1];
    const float* V  = (const float*)d_in[2];
    const int*   VL = (const int*)d_in[3];
    float* O = (float*)d_out;

    const int B = in_sizes[3];
    const int n = in_sizes[0] / (B * DHEAD);
    const int m = in_sizes[1] / (B * DHEAD);
    const int rows = B * n;

    const size_t kv_elems = (size_t)B * m * DHEAD;
    short* Kz = (short*)d_ws;
    short* Vz = Kz + kv_elems;
    const size_t used = 2 * kv_elems * sizeof(short);   // 8 MB

    // KV-split factor by remaining workspace (OP bf16 + ML fp32)
    const size_t per_chunk = (size_t)rows * (DHEAD * 2 + 8);
    int S = 1;
    if (ws_size >= used + 4 * per_chunk) S = 4;
    else if (ws_size >= used + 2 * per_chunk) S = 2;

    short*  OPb = (short*)((char*)d_ws + used);
    float2* ML  = (float2*)((char*)d_ws + used + (size_t)S * rows * DHEAD * 2);

    const int nvec = (int)(kv_elems / 8);
    prep_bf16<<<(2 * nvec + 255) / 256, 256, 0, stream>>>(K, V, Kz, Vz, nvec);

    const int grid = B * (n / 32) * S;
    attn_fwd<<<grid, 128, 0, stream>>>(Q, Kz, Vz, VL, O, OPb, ML, B, n, m, S, rows);
    if (S > 1)
        attn_combine<<<rows, 128, 0, stream>>>(OPb, ML, O, S, rows);
}

// Round 5
// 33.765 us; speedup vs baseline: 1.5345x; 1.5345x over previous
//
#include <hip/hip_runtime.h>
#include <hip/hip_bf16.h>

typedef __attribute__((ext_vector_type(4))) float f32x4;
typedef __attribute__((ext_vector_type(8))) short s16x8;
typedef __attribute__((ext_vector_type(4))) short s16x4;

#define KVBLK 64
#define DHEAD 128
#define KSTR 136   // K LDS row stride (272 B)
#define VSTR 72    // V^T LDS row stride (144 B)
#define BLKQ 128   // q-rows per block = 8 waves x 16

__device__ __forceinline__ short f2bf(float x) {
    __hip_bfloat16 h = __float2bfloat16(x);
    return *reinterpret_cast<short*>(&h);
}

// Flash attention. Block = 8 waves x 16 q-rows = 128 q-rows, KVBLK = 64.
// K/V staged f32->bf16 once per block-tile (amortized over 128 q-rows, 4x less
// L2 traffic than 32-row blocks). T14: next tile's f32 loads issued before
// compute of current tile. Cyclic KV-split S with f32 partials + combine.
__global__ __launch_bounds__(512, 1)
void attn_fwd(const float* __restrict__ Q, const float* __restrict__ K,
              const float* __restrict__ V, const int* __restrict__ VL,
              float* __restrict__ O, float* __restrict__ OP, float2* __restrict__ ML,
              int B, int n, int m, int S, int rows) {
    __shared__ short Ks[KVBLK * KSTR];   // 17408 B
    __shared__ short Vs[DHEAD * VSTR];   // 18432 B

    const int tid  = threadIdx.x;
    const int lane = tid & 63;
    const int wid  = tid >> 6;     // 0..7
    const int g    = lane >> 4;    // 0..3
    const int qi   = lane & 15;

    const int nq = n >> 7;         // q-tiles of 128 rows
    int b, rest;
    if ((B & 7) == 0) {
        const int xcd = blockIdx.x & 7;
        const int sub = blockIdx.x >> 3;
        const int bpx = B >> 3;
        b    = xcd * bpx + (sub % bpx);
        rest = sub / bpx;
    } else {
        const int per = nq * S;
        b    = blockIdx.x / per;
        rest = blockIdx.x % per;
    }
    const int qt = rest / S;
    const int c  = rest - qt * S;

    const int vl = VL[b];
    const int nt = (vl + KVBLK - 1) >> 6;
    const int rowbase = b * n + qt * BLKQ + wid * 16;

    if (c >= nt) {   // empty chunk (cyclic: chunk c owns tiles c, c+S, ...)
        if (S > 1 && g == 0) ML[(size_t)c * rows + rowbase + qi] = make_float2(-1e30f, 0.f);
        return;
    }

    const float* Qb = Q + (size_t)rowbase * DHEAD;
    const float* Kb = K + (size_t)b * m * DHEAD;
    const float* Vb = V + (size_t)b * m * DHEAD;

    // staging assignments (one pass, 512 threads)
    const int krow = tid >> 3;          // 0..63
    const int kcol = (tid & 7) << 4;    // 0,16,...,112
    const int kv4  = tid >> 5;          // 0..15 (kv quad)
    const int dvg  = tid & 31;          // 0..31 (dv quad)

    // ---- Q fragments, pre-scaled by 1/sqrt(d)*log2(e) ----
    const float qsc = 0.08838834764831845f * 1.4426950408889634f;
    s16x8 qf[4];
    {
        const float* qp = Qb + qi * DHEAD + g * 8;
        #pragma unroll
        for (int kk = 0; kk < 4; ++kk) {
            f32x4 a  = *reinterpret_cast<const f32x4*>(qp + kk * 32);
            f32x4 cc = *reinterpret_cast<const f32x4*>(qp + kk * 32 + 4);
            s16x8 s;
            #pragma unroll
            for (int j = 0; j < 4; ++j) { s[j] = f2bf(a[j] * qsc); s[4 + j] = f2bf(cc[j] * qsc); }
            qf[kk] = s;
        }
    }

    // V^T read element offsets (swizzle folded in)
    int voff[8];
    #pragma unroll
    for (int dg = 0; dg < 8; ++dg) {
        const int row = qi + (dg << 4);
        voff[dg] = row * VSTR + ((g << 2) ^ (((row >> 3) & 3) << 2));
    }
    const int kbase = qi * KSTR + (g << 3);

    f32x4 Oacc[8];
    #pragma unroll
    for (int dg = 0; dg < 8; ++dg) Oacc[dg] = 0.f;
    float mrun = -1e30f, lrun = 0.f;

    // ---- prologue: issue f32 loads for first tile (T14) ----
    f32x4 kpre[4], vpre[4];
    {
        const float* kp = Kb + (size_t)(c * KVBLK + krow) * DHEAD + kcol;
        #pragma unroll
        for (int j = 0; j < 4; ++j) kpre[j] = *reinterpret_cast<const f32x4*>(kp + 4 * j);
        const float* vp = Vb + (size_t)(c * KVBLK + (kv4 << 2)) * DHEAD + (dvg << 2);
        #pragma unroll
        for (int r = 0; r < 4; ++r) vpre[r] = *reinterpret_cast<const f32x4*>(vp + r * DHEAD);
    }

    #pragma unroll 1
    for (int t = c; t < nt; t += S) {
        const int base = t * KVBLK;
        __syncthreads();   // all waves done reading previous tile's LDS

        // ---- convert + write K tile ----
        {
            s16x8 s0, s1;
            #pragma unroll
            for (int j = 0; j < 4; ++j) {
                s0[j] = f2bf(kpre[0][j]); s0[4 + j] = f2bf(kpre[1][j]);
                s1[j] = f2bf(kpre[2][j]); s1[4 + j] = f2bf(kpre[3][j]);
            }
            *reinterpret_cast<s16x8*>(&Ks[krow * KSTR + kcol])     = s0;
            *reinterpret_cast<s16x8*>(&Ks[krow * KSTR + kcol + 8]) = s1;
        }
        // ---- convert + write V^T tile (swizzled) ----
        #pragma unroll
        for (int jj = 0; jj < 4; ++jj) {
            const int dvr = (dvg << 2) + jj;
            s16x4 sv;
            sv[0] = f2bf(vpre[0][jj]); sv[1] = f2bf(vpre[1][jj]);
            sv[2] = f2bf(vpre[2][jj]); sv[3] = f2bf(vpre[3][jj]);
            *reinterpret_cast<s16x4*>(&Vs[dvr * VSTR + ((kv4 << 2) ^ (((dvr >> 3) & 3) << 2))]) = sv;
        }
        __syncthreads();   // tile visible

        // ---- prefetch next tile's f32 (lands during compute below) ----
        const int tn = t + S;
        if (tn < nt) {
            const float* kp = Kb + (size_t)(tn * KVBLK + krow) * DHEAD + kcol;
            #pragma unroll
            for (int j = 0; j < 4; ++j) kpre[j] = *reinterpret_cast<const f32x4*>(kp + 4 * j);
            const float* vp = Vb + (size_t)(tn * KVBLK + (kv4 << 2)) * DHEAD + (dvg << 2);
            #pragma unroll
            for (int r = 0; r < 4; ++r) vpre[r] = *reinterpret_cast<const f32x4*>(vp + r * DHEAD);
        }

        // ---- S^T = K * Q^T : rows kv = 16s+4g+r, col q = qi ----
        f32x4 Sacc[4];
        #pragma unroll
        for (int s = 0; s < 4; ++s) Sacc[s] = 0.f;
        #pragma unroll
        for (int s = 0; s < 4; ++s)
            #pragma unroll
            for (int kk = 0; kk < 4; ++kk) {
                s16x8 kf = *reinterpret_cast<const s16x8*>(&Ks[kbase + s * 16 * KSTR + kk * 32]);
                Sacc[s] = __builtin_amdgcn_mfma_f32_16x16x32_bf16(kf, qf[kk], Sacc[s], 0, 0, 0);
            }

        // ---- valid_length mask ----
        const int kvrem = vl - base;
        if (kvrem < KVBLK) {
            #pragma unroll
            for (int s = 0; s < 4; ++s)
                #pragma unroll
                for (int r = 0; r < 4; ++r)
                    if (s * 16 + g * 4 + r >= kvrem) Sacc[s][r] = -1e30f;
        }

        // ---- online softmax (state per lane for q = qi, replicated x4 groups) ----
        float tmax = -1e30f;
        #pragma unroll
        for (int s = 0; s < 4; ++s)
            #pragma unroll
            for (int r = 0; r < 4; ++r) tmax = fmaxf(tmax, Sacc[s][r]);
        tmax = fmaxf(tmax, __shfl_xor(tmax, 16));
        tmax = fmaxf(tmax, __shfl_xor(tmax, 32));
        const float mnew = fmaxf(mrun, tmax);
        const float corr = __builtin_amdgcn_exp2f(mrun - mnew);

        float psum = 0.f;
        #pragma unroll
        for (int s = 0; s < 4; ++s)
            #pragma unroll
            for (int r = 0; r < 4; ++r) {
                const float e = __builtin_amdgcn_exp2f(Sacc[s][r] - mnew);
                Sacc[s][r] = e; psum += e;
            }
        psum += __shfl_xor(psum, 16);
        psum += __shfl_xor(psum, 32);
        lrun = lrun * corr + psum;
        mrun = mnew;

        // pack P -> bf16 A-fragments (kv order consistent with V^T reads)
        s16x8 pa[2];
        #pragma unroll
        for (int h = 0; h < 2; ++h)
            #pragma unroll
            for (int r = 0; r < 4; ++r) {
                pa[h][r]     = f2bf(Sacc[2 * h][r]);
                pa[h][4 + r] = f2bf(Sacc[2 * h + 1][r]);
            }

        // rescale O accumulators
        const float rr0 = __shfl(corr, g * 4 + 0);
        const float rr1 = __shfl(corr, g * 4 + 1);
        const float rr2 = __shfl(corr, g * 4 + 2);
        const float rr3 = __shfl(corr, g * 4 + 3);
        #pragma unroll
        for (int dg = 0; dg < 8; ++dg) {
            Oacc[dg][0] *= rr0; Oacc[dg][1] *= rr1;
            Oacc[dg][2] *= rr2; Oacc[dg][3] *= rr3;
        }

        // ---- O += P * V ----
        #pragma unroll
        for (int dg = 0; dg < 8; ++dg) {
            #pragma unroll
            for (int kk = 0; kk < 2; ++kk) {
                s16x4 v0 = *reinterpret_cast<const s16x4*>(&Vs[voff[dg] + (kk << 5)]);
                s16x4 v1 = *reinterpret_cast<const s16x4*>(&Vs[voff[dg] + (kk << 5) + 16]);
                s16x8 vf;
                vf[0] = v0[0]; vf[1] = v0[1]; vf[2] = v0[2]; vf[3] = v0[3];
                vf[4] = v1[0]; vf[5] = v1[1]; vf[6] = v1[2]; vf[7] = v1[3];
                Oacc[dg] = __builtin_amdgcn_mfma_f32_16x16x32_bf16(pa[kk], vf, Oacc[dg], 0, 0, 0);
            }
        }
    }

    if (S > 1) {
        if (g == 0) ML[(size_t)c * rows + rowbase + qi] = make_float2(mrun, lrun);
        float* Op = OP + ((size_t)c * rows + rowbase) * DHEAD;
        #pragma unroll
        for (int dg = 0; dg < 8; ++dg) {
            Op[(g * 4 + 0) * DHEAD + dg * 16 + qi] = Oacc[dg][0];
            Op[(g * 4 + 1) * DHEAD + dg * 16 + qi] = Oacc[dg][1];
            Op[(g * 4 + 2) * DHEAD + dg * 16 + qi] = Oacc[dg][2];
            Op[(g * 4 + 3) * DHEAD + dg * 16 + qi] = Oacc[dg][3];
        }
    } else {
        const float linv = 1.0f / lrun;
        const float l0 = __shfl(linv, g * 4 + 0);
        const float l1 = __shfl(linv, g * 4 + 1);
        const float l2 = __shfl(linv, g * 4 + 2);
        const float l3 = __shfl(linv, g * 4 + 3);
        float* Ob = O + (size_t)rowbase * DHEAD;
        #pragma unroll
        for (int dg = 0; dg < 8; ++dg) {
            Ob[(g * 4 + 0) * DHEAD + dg * 16 + qi] = Oacc[dg][0] * l0;
            Ob[(g * 4 + 1) * DHEAD + dg * 16 + qi] = Oacc[dg][1] * l1;
            Ob[(g * 4 + 2) * DHEAD + dg * 16 + qi] = Oacc[dg][2] * l2;
            Ob[(g * 4 + 3) * DHEAD + dg * 16 + qi] = Oacc[dg][3] * l3;
        }
    }
}

// merge S partials (O, m, l) per q-row
__global__ __launch_bounds__(128)
void attn_combine(const float* __restrict__ OP, const float2* __restrict__ ML,
                  float* __restrict__ O, int S, int rows) {
    const int row = blockIdx.x;
    const int t   = threadIdx.x;
    float M = -1e30f;
    for (int s = 0; s < S; ++s) M = fmaxf(M, ML[(size_t)s * rows + row].x);
    float L = 0.f, acc = 0.f;
    for (int s = 0; s < S; ++s) {
        const float2 ml = ML[(size_t)s * rows + row];
        if (ml.y > 0.f) {
            const float w = exp2f(ml.x - M);
            L += ml.y * w;
            acc += w * OP[((size_t)s * rows + row) * DHEAD + t];
        }
    }
    O[(size_t)row * DHEAD + t] = acc / L;
}

extern "C" void kernel_launch(void* const* d_in, const int* in_sizes, int n_in,
                              void* d_out, int out_size, void* d_ws, size_t ws_size,
                              hipStream_t stream) {
    const float* Q  = (const float*)d_in[0];
    const float* K  = (const float*)d_in[1];
    const float* V  = (const float*)d_in[2];
    const int*   VL = (const int*)d_in[3];
    float* O = (float*)d_out;

    const int B = in_sizes[3];
    const int n = in_sizes[0] / (B * DHEAD);
    const int m = in_sizes[1] / (B * DHEAD);
    const int rows = B * n;

    const size_t per_chunk = (size_t)rows * (DHEAD * 4 + 8);
    const int S = (ws_size >= 2 * per_chunk) ? 2 : 1;

    float*  OP = (float*)d_ws;
    float2* ML = (float2*)((char*)d_ws + (size_t)S * rows * DHEAD * 4);

    const int grid = B * (n / BLKQ) * S;
    attn_fwd<<<grid, 512, 0, stream>>>(Q, K, V, VL, O, OP, ML, B, n, m, S, rows);
    if (S > 1)
        attn_combine<<<rows, 128, 0, stream>>>(OP, ML, O, S, rows);
}